// Round 2
// baseline (307.516 us; speedup 1.0000x reference)
//
#include <hip/hip_runtime.h>

#define GSZ   16
#define NVOX  4096        // 16^3
#define BB    4
#define DD    128
#define PThr  1024        // prep threads
#define PPT   4           // points per prep thread
#define PTILE (PThr * PPT) // 4096 points per prep tile
#define SS    4           // point-range split for scatter
#define SThr  512         // scatter threads per block

typedef __fp16 half2v __attribute__((ext_vector_type(2)));

// packed f16 LDS atomic add: adds (va,vb) to the half2 at LDS byte offset.
__device__ __forceinline__ void lds_pk_add_f16(unsigned byte_off, float va, float vb) {
    half2v h = __builtin_amdgcn_cvt_pkrtz(va, vb);
    unsigned hv;
    __builtin_memcpy(&hv, &h, 4);
    asm volatile("ds_pk_add_f16 %0, %1" : : "v"(byte_off), "v"(hv) : "memory");
}

// ---------------------------------------------------------------------------
// Dispatch 1: voxel idx per point (u16, 0xFFFF = masked) + per-tile u16
// histograms. 1024 thr x 4 pts => 16 waves/block, 100 blocks (4x the waves
// of the old 256x16 version, same NT/histg structure).
// ---------------------------------------------------------------------------
__global__ __launch_bounds__(PThr) void k_prep(const float* __restrict__ xyz,
                                               const int* __restrict__ mask,
                                               unsigned short* __restrict__ idxm,
                                               unsigned short* __restrict__ histg,
                                               int N, int NT) {
    __shared__ unsigned int hist[NVOX];
    const int tile = blockIdx.x, b = blockIdx.y;
    for (int j = threadIdx.x; j < NVOX; j += PThr) hist[j] = 0u;
    __syncthreads();

    const float*    xb = xyz  + (size_t)b * N * 3;
    const int*      mb = mask + (size_t)b * N;
    unsigned short* ib = idxm + (size_t)b * N;

    const int p0 = tile * PTILE + (int)threadIdx.x * PPT;

    if (p0 + PPT <= N) {
        float a[3 * PPT];
        float4* av = (float4*)a;
        const float4* xv = (const float4*)(xb + 3 * (size_t)p0);
#pragma unroll
        for (int q = 0; q < 3; q++) av[q] = xv[q];
        int4 m4 = *(const int4*)(mb + p0);
        int mk[PPT] = { m4.x, m4.y, m4.z, m4.w };
        alignas(8) unsigned short pk[PPT];
#pragma unroll
        for (int k = 0; k < PPT; k++) {
            int vx = min(max((int)(a[3*k+0] * (float)GSZ), 0), GSZ - 1);
            int vy = min(max((int)(a[3*k+1] * (float)GSZ), 0), GSZ - 1);
            int vz = min(max((int)(a[3*k+2] * (float)GSZ), 0), GSZ - 1);
            int idx = vz * GSZ * GSZ + vy * GSZ + vx;
            if (mk[k] != 0) {
                pk[k] = (unsigned short)idx;
                atomicAdd(&hist[idx], 1u);
            } else {
                pk[k] = 0xFFFFu;
            }
        }
        *(uint2*)(ib + p0) = *(const uint2*)pk;
    } else {
        for (int k = 0; k < PPT; k++) {
            int p = p0 + k;
            if (p >= N) break;
            float x = xb[3*(size_t)p+0], y = xb[3*(size_t)p+1], z = xb[3*(size_t)p+2];
            int vx = min(max((int)(x * (float)GSZ), 0), GSZ - 1);
            int vy = min(max((int)(y * (float)GSZ), 0), GSZ - 1);
            int vz = min(max((int)(z * (float)GSZ), 0), GSZ - 1);
            int idx = vz * GSZ * GSZ + vy * GSZ + vx;
            if (mb[p] != 0) { ib[p] = (unsigned short)idx; atomicAdd(&hist[idx], 1u); }
            else            { ib[p] = 0xFFFFu; }
        }
    }
    __syncthreads();
    unsigned short* hg = histg + ((size_t)b * NT + tile) * NVOX;
    for (int j = threadIdx.x; j < NVOX; j += PThr) hg[j] = (unsigned short)hist[j];
}

// ---------------------------------------------------------------------------
// Dispatch 2: per-voxel reciprocal counts (summed across tile histograms).
// grid = BB*NVOX/1024 = 16 blocks.
// ---------------------------------------------------------------------------
__global__ __launch_bounds__(1024) void k_counts(const unsigned short* __restrict__ histg,
                                                 float* __restrict__ rinv, int NT) {
    const int gid = blockIdx.x * 1024 + (int)threadIdx.x;   // [0, BB*NVOX)
    const int b = gid >> 12, v = gid & (NVOX - 1);
    const unsigned short* hb = histg + (size_t)b * NT * NVOX + v;
    int c = 0, t = 0;
    for (; t + 4 <= NT; t += 4) {
        int c0 = hb[(size_t)(t+0)*NVOX];
        int c1 = hb[(size_t)(t+1)*NVOX];
        int c2 = hb[(size_t)(t+2)*NVOX];
        int c3 = hb[(size_t)(t+3)*NVOX];
        c += c0 + c1 + c2 + c3;
    }
    for (; t < NT; t++) c += hb[(size_t)t*NVOX];
    rinv[gid] = 1.0f / (float)max(c, 1);
}

// ---------------------------------------------------------------------------
// Dispatch 3: partial scatter. Each block owns (s, b, d-pair): accumulates its
// quarter of the point range into a 16 KB half2 LDS accumulator, then dumps
// the raw packed sums to workspace. 1024 blocks x 512 thr, >=3 blocks/CU.
// ---------------------------------------------------------------------------
__global__ __launch_bounds__(SThr, 6) void k_scatter(const float* __restrict__ feats,
                                                     const unsigned short* __restrict__ idxm,
                                                     unsigned int* __restrict__ partial,
                                                     int N, int Q) {
    __shared__ half2v acc[NVOX];     // 16 KB
    const int bid = blockIdx.x;      // = s*256 + b*64 + dp
    const int dp  = bid & 63;
    const int b   = (bid >> 6) & (BB - 1);
    const int s   = bid >> 8;
    const int d0  = dp * 2;

    {
        half2v z = { (__fp16)0.f, (__fp16)0.f };
        for (int j = threadIdx.x; j < NVOX; j += SThr) acc[j] = z;
    }
    __syncthreads();

    const int start = s * Q;
    const int end   = min(start + Q, N);
    const int cnt   = end - start;

    const unsigned short* ib = idxm + (size_t)b * N;
    const float* f0 = feats + ((size_t)b * DD + (size_t)d0) * (size_t)N;
    const float* f1 = f0 + N;
    const unsigned accbase = (unsigned)(size_t)(void*)&acc[0];

#define PROC(idx_, va_, vb_)                                       \
    {                                                              \
        unsigned _i = (idx_);                                      \
        if (_i != 0xFFFFu) lds_pk_add_f16(accbase + _i * 4u, (va_), (vb_)); \
    }

    const int nfull = cnt > 0 ? cnt / (SThr * 8) : 0;
    const int t8    = (int)threadIdx.x * 8;

    for (int it = 0; it < nfull; it++) {
        const int p = start + it * (SThr * 8) + t8;
        uint4  iv = *(const uint4*)(ib + p);
        float4 a0 = *(const float4*)(f0 + p);
        float4 a1 = *(const float4*)(f0 + p + 4);
        float4 b0 = *(const float4*)(f1 + p);
        float4 b1 = *(const float4*)(f1 + p + 4);

        PROC(iv.x & 0xFFFFu, a0.x, b0.x)
        PROC(iv.x >> 16,     a0.y, b0.y)
        PROC(iv.y & 0xFFFFu, a0.z, b0.z)
        PROC(iv.y >> 16,     a0.w, b0.w)
        PROC(iv.z & 0xFFFFu, a1.x, b1.x)
        PROC(iv.z >> 16,     a1.y, b1.y)
        PROC(iv.w & 0xFFFFu, a1.z, b1.z)
        PROC(iv.w >> 16,     a1.w, b1.w)
    }
    for (int p = start + nfull * (SThr * 8) + (int)threadIdx.x; p < end; p += SThr) {
        unsigned id = ib[p];
        if (id != 0xFFFFu) lds_pk_add_f16(accbase + id * 4u, f0[p], f1[p]);
    }
#undef PROC

    __syncthreads();

    unsigned int* pb = partial + (size_t)bid * NVOX;
    for (int j = threadIdx.x; j < NVOX; j += SThr) {
        half2v h = acc[j];
        unsigned w;
        __builtin_memcpy(&w, &h, 4);
        pb[j] = w;       // coalesced u32 stores, lane-stride-1 LDS reads
    }
}

// ---------------------------------------------------------------------------
// Dispatch 4: combine SS partials, apply reciprocal count, write out.
// grid = BB*DD/2 = 256 blocks x 1024 thr (4 voxels/thread).
// ---------------------------------------------------------------------------
__global__ __launch_bounds__(1024) void k_combine(const unsigned int* __restrict__ partial,
                                                  const float* __restrict__ rinv,
                                                  float* __restrict__ out) {
    const int bid = blockIdx.x;          // b*64 + dp
    const int dp  = bid & 63;
    const int b   = bid >> 6;
    const int d0  = dp * 2;
    const int v0  = (int)threadIdx.x * 4;

    float s0[4] = {0.f, 0.f, 0.f, 0.f};
    float s1[4] = {0.f, 0.f, 0.f, 0.f};
#pragma unroll
    for (int s = 0; s < SS; s++) {
        uint4 P = *(const uint4*)(partial + ((size_t)(s * BB * 64 + bid)) * NVOX + v0);
        unsigned w[4] = { P.x, P.y, P.z, P.w };
#pragma unroll
        for (int j = 0; j < 4; j++) {
            half2v h;
            __builtin_memcpy(&h, &w[j], 4);
            s0[j] += (float)h.x;
            s1[j] += (float)h.y;
        }
    }
    float4 rv = *(const float4*)(rinv + (size_t)b * NVOX + v0);
    float r[4] = { rv.x, rv.y, rv.z, rv.w };
    float4 oa, ob;
    oa.x = s0[0]*r[0];  ob.x = s1[0]*r[0];
    oa.y = s0[1]*r[1];  ob.y = s1[1]*r[1];
    oa.z = s0[2]*r[2];  ob.z = s1[2]*r[2];
    oa.w = s0[3]*r[3];  ob.w = s1[3]*r[3];
    float* r0 = out + ((size_t)b * DD + (size_t)d0) * (size_t)NVOX + v0;
    *(float4*)r0          = oa;
    *(float4*)(r0 + NVOX) = ob;
}

extern "C" void kernel_launch(void* const* d_in, const int* in_sizes, int n_in,
                              void* d_out, int out_size, void* d_ws, size_t ws_size,
                              hipStream_t stream) {
    const float* feats = (const float*)d_in[0];          // [B, D, N]
    const float* xyz   = (const float*)d_in[1];          // [B, N, 3]
    const int*   mask  = (const int*)d_in[2];            // [B, N]
    float*       out   = (float*)d_out;                  // [B, D, V]

    int N  = in_sizes[2] / BB;                           // mask is B*N
    int NT = (N + PTILE - 1) / PTILE;
    int Q  = (((N + SS - 1) / SS) + 7) & ~7;             // 8-aligned chunk => 16B-aligned ptrs

    // workspace carve — everything fully overwritten each call, no memsets
    char* w = (char*)d_ws;
    unsigned short* idxm  = (unsigned short*)w;          // B*N u16
    w += (((size_t)BB * N * sizeof(unsigned short)) + 255) & ~(size_t)255;
    unsigned short* histg = (unsigned short*)w;          // B*NT*NVOX u16
    w += (((size_t)BB * NT * NVOX * sizeof(unsigned short)) + 255) & ~(size_t)255;
    float*          rinv  = (float*)w;                   // B*NVOX f32
    w += (((size_t)BB * NVOX * sizeof(float)) + 255) & ~(size_t)255;
    unsigned int*   part  = (unsigned int*)w;            // SS*B*64*NVOX u32 (16.8 MB)

    k_prep   <<<dim3(NT, BB), PThr, 0, stream>>>(xyz, mask, idxm, histg, N, NT);
    k_scatter<<<SS * BB * (DD / 2), SThr, 0, stream>>>(feats, idxm, part, N, Q);
    k_counts <<<(BB * NVOX) / 1024, 1024, 0, stream>>>(histg, rinv, NT);
    k_combine<<<BB * (DD / 2), 1024, 0, stream>>>(part, rinv, out);
}